// Round 10
// baseline (521.354 us; speedup 1.0000x reference)
//
#include <hip/hip_runtime.h>
#include <hip/hip_bf16.h>
#include <cstdint>

typedef __hip_bfloat16 bf16;

constexpr int Bb = 16, Nn = 128, Ll = 512, Dd = 1024, Ss = 16, Rr = 64, Hh = 2048;
constexpr int Mm = Bb * Nn; // 2048 rows

using bf16x8 = __attribute__((ext_vector_type(8))) __bf16;
using f32x4  = __attribute__((ext_vector_type(4))) float;

__device__ __forceinline__ float to_f(float x) { return x; }
__device__ __forceinline__ float to_f(bf16 x) { return __bfloat162float(x); }
__device__ __forceinline__ void store_t(float* p, float v) { *p = v; }
__device__ __forceinline__ void store_t(bf16* p, float v) { *p = __float2bfloat16(v); }
__device__ __forceinline__ __bf16 cvt1(float x) {
  bf16 h = __float2bfloat16(x);
  return *reinterpret_cast<__bf16*>(&h);
}
__device__ __forceinline__ bf16x8 load8(const bf16* p) { return *(const bf16x8*)p; }
__device__ __forceinline__ bf16x8 load8(const float* p) {
  float4 a = *(const float4*)p;
  float4 b = *(const float4*)(p + 4);
  bf16x8 r;
  r[0] = cvt1(a.x); r[1] = cvt1(a.y); r[2] = cvt1(a.z); r[3] = cvt1(a.w);
  r[4] = cvt1(b.x); r[5] = cvt1(b.y); r[6] = cvt1(b.z); r[7] = cvt1(b.w);
  return r;
}

enum { EPI_STORE = 0, EPI_BIAS_RELU = 1, EPI_ADD = 3, EPI_BIAS = 4, EPI_BIAS_SOFTPLUS = 5,
       EPI_ATOMIC = 6 };

// ---- dtype sniffer --------------------------------------------------------
__global__ void sniff_kernel(const unsigned short* __restrict__ xs, int* __restrict__ flags) {
  const int tid = threadIdx.x;
  int cnt = 0;
  for (int j = 0; j < 64; ++j) {
    int i = tid + j * 256;
    unsigned short u = xs[(size_t)i * 64];
    bf16 h = *reinterpret_cast<bf16*>(&u);
    float v = __bfloat162float(h);
    float a = fabsf(v);
    if (v == 0.f || (a > 0.0009765625f && a < 16.f)) ++cnt;
  }
  __shared__ int sc[256];
  sc[tid] = cnt;
  __syncthreads();
  for (int o = 128; o > 0; o >>= 1) {
    if (tid < o) sc[tid] += sc[tid + o];
    __syncthreads();
  }
  if (tid == 0) flags[0] = (sc[0] > 8192) ? 1 : 0; // 1 = bf16, 0 = f32
}

// ---- MFMA GEMM v2.1: 64x64 tile, BK=64, 4 waves x (2x2 16x16x32) ----------
// C(M,N) = A(M,K) @ Bw(N,K)^T. Identical math/epilogue to the R8 (green) kernel;
// only change: XCD-aware block swizzle when gridDim.x is a multiple of 8.
// id%8 = XCD on MI355X round-robin dispatch; each XCD then owns a contiguous
// 8-wide n-stripe so its private L2 re-serves the B-panels.
constexpr int LDT2 = 72; // row stride el: 144 B, 16B-aligned
template <typename TA, typename TW, typename TC, int EPI>
__global__ __launch_bounds__(256) void gemm_mfma(const int* __restrict__ flagp, int want,
                                                 const TA* __restrict__ A, int lda,
                                                 const TW* __restrict__ Bw, int ldb,
                                                 TC* __restrict__ C, int ldc,
                                                 const TW* __restrict__ bias,
                                                 int N, int Kchunk) {
  if (*flagp != want) return;
  __shared__ __align__(16) __bf16 As[64 * LDT2];
  __shared__ __align__(16) __bf16 Bs[64 * LDT2];
  const int tid = threadIdx.x;
  const int wave = tid >> 6, lane = tid & 63;
  const int quad = lane >> 4, l16 = lane & 15;
  const int wm = wave & 1, wn = wave >> 1;
  int bx = blockIdx.x, by = blockIdx.y;
  const int gx = gridDim.x, gy = gridDim.y;
  if ((gx & 7) == 0) { // XCD swizzle (bijection; see R9 analysis)
    int id = bx + gx * by;
    int xcd = id & 7, sl = id >> 3;
    by = sl % gy;
    bx = (sl / gy) * 8 + xcd;
  }
  const int m0 = by * 64, n0 = bx * 64;
  const int kb = blockIdx.z * Kchunk;
  const int srow = tid >> 3;      // 0..31
  const int scol = (tid & 7) * 8; // 0..56
  f32x4 acc[2][2] = {};
  for (int k0 = kb; k0 < kb + Kchunk; k0 += 64) {
#pragma unroll
    for (int h = 0; h < 2; ++h) {
      int r = srow + h * 32;
      *(bf16x8*)(&As[r * LDT2 + scol]) = load8(A + (size_t)(m0 + r) * lda + k0 + scol);
      int rb = n0 + r;
      rb = rb < N ? rb : N - 1; // clamp (ragged N); garbage cols masked in epilogue
      *(bf16x8*)(&Bs[r * LDT2 + scol]) = load8(Bw + (size_t)rb * ldb + k0 + scol);
    }
    __syncthreads();
#pragma unroll
    for (int kk = 0; kk < 2; ++kk) {
      bf16x8 af[2], bfr[2];
#pragma unroll
      for (int i = 0; i < 2; ++i)
        af[i] = *(const bf16x8*)(&As[(wm * 32 + i * 16 + l16) * LDT2 + kk * 32 + quad * 8]);
#pragma unroll
      for (int j = 0; j < 2; ++j)
        bfr[j] = *(const bf16x8*)(&Bs[(wn * 32 + j * 16 + l16) * LDT2 + kk * 32 + quad * 8]);
#pragma unroll
      for (int i = 0; i < 2; ++i)
#pragma unroll
        for (int j = 0; j < 2; ++j)
          acc[i][j] = __builtin_amdgcn_mfma_f32_16x16x32_bf16(af[i], bfr[j], acc[i][j], 0, 0, 0);
    }
    __syncthreads();
  }
#pragma unroll
  for (int i = 0; i < 2; ++i) {
#pragma unroll
    for (int j = 0; j < 2; ++j) {
      const int col = n0 + wn * 32 + j * 16 + l16;
      if (col >= N) continue;
      float bv = 0.f;
      if (EPI == EPI_BIAS_RELU || EPI == EPI_BIAS || EPI == EPI_BIAS_SOFTPLUS) bv = to_f(bias[col]);
#pragma unroll
      for (int r = 0; r < 4; ++r) {
        const int row = m0 + wm * 32 + i * 16 + quad * 4 + r;
        size_t idx = (size_t)row * ldc + col;
        float v = acc[i][j][r];
        if (EPI == EPI_STORE) store_t(&C[idx], v);
        else if (EPI == EPI_BIAS_RELU) { v += bv; store_t(&C[idx], v > 0.f ? v : 0.f); }
        else if (EPI == EPI_ADD) ((float*)C)[idx] += v;        // TC=float only
        else if (EPI == EPI_BIAS) store_t(&C[idx], v + bv);
        else if (EPI == EPI_BIAS_SOFTPLUS) {
          v += bv;
          store_t(&C[idx], (v > 20.f) ? v : log1pf(__expf(v)));
        } else if (EPI == EPI_ATOMIC) {
          atomicAdd((float*)&C[idx], v);                        // TC=float only
        }
      }
    }
  }
}

// ---- zero helper (not flag-gated: shared f32 region, runs in both paths) ---
__global__ __launch_bounds__(256) void zero_kernel(float4* __restrict__ p, int n4) {
  int i = blockIdx.x * 256 + threadIdx.x;
  if (i < n4) p[i] = float4{0.f, 0.f, 0.f, 0.f};
}

// ---- depthwise conv + SiLU (trusted R3) -----------------------------------
template <typename TW>
__global__ __launch_bounds__(256) void conv_silu_kernel(const int* __restrict__ flagp, int want,
                                                        const float* __restrict__ X2,
                                                        const TW* __restrict__ cw,
                                                        const TW* __restrict__ cb,
                                                        float* __restrict__ XC, int dir) {
  if (*flagp != want) return;
  const int d = blockIdx.y * 256 + threadIdx.x;
  const int m = blockIdx.x;
  const int t = m & (Nn - 1);
  float w0 = to_f(cw[d * 4 + 0]), w1 = to_f(cw[d * 4 + 1]);
  float w2 = to_f(cw[d * 4 + 2]), w3 = to_f(cw[d * 4 + 3]);
  float a = to_f(cb[d]);
  if (dir == 0) {
    if (t >= 3) a += w0 * X2[(size_t)(m - 3) * 2048 + d];
    if (t >= 2) a += w1 * X2[(size_t)(m - 2) * 2048 + d];
    if (t >= 1) a += w2 * X2[(size_t)(m - 1) * 2048 + d];
    a += w3 * X2[(size_t)m * 2048 + d];
  } else {
    if (t + 3 < Nn) a += w0 * X2[(size_t)(m + 3) * 2048 + d];
    if (t + 2 < Nn) a += w1 * X2[(size_t)(m + 2) * 2048 + d];
    if (t + 1 < Nn) a += w2 * X2[(size_t)(m + 1) * 2048 + d];
    a += w3 * X2[(size_t)m * 2048 + d];
  }
  XC[(size_t)m * 1024 + d] = a / (1.f + __expf(-a));
}

// ---- selective scan (R7, trusted): DELTA precomputed, Bm/Cm LDS, prefetch --
template <typename TW>
__global__ __launch_bounds__(256) void scan_gate_kernel(
    const int* __restrict__ flagp, int want,
    const float* __restrict__ DBC, float* __restrict__ XC, const float* __restrict__ X2,
    const bf16* __restrict__ DELTA,
    const TW* __restrict__ A_log, const TW* __restrict__ Dp, int dir) {
  if (*flagp != want) return;
  __shared__ __align__(16) float sBC[Nn * 32]; // Bm|Cm per t: 16 KB
  const int b = blockIdx.x;
  const int dblk = blockIdx.y;
  const int tid = threadIdx.x;
  {
    const float* src = DBC + (size_t)b * Nn * 96;
#pragma unroll
    for (int k2 = 0; k2 < 16; ++k2) {
      int f = tid + k2 * 256;
      int r = f >> 5, c = f & 31;
      sBC[f] = src[r * 96 + 64 + c];
    }
  }
  __syncthreads();
  const int lane = tid & 63, wave = tid >> 6;
  const int dl = lane & 15, sg = lane >> 4;
  const int d = dblk * 64 + wave * 16 + dl;
  float A_[4];
#pragma unroll
  for (int j = 0; j < 4; ++j) A_[j] = -__expf(to_f(A_log[d * Ss + sg * 4 + j]));
  const float dp = to_f(Dp[d]);
  const size_t rowbase = (size_t)b * Nn;
  int t = dir ? (Nn - 1) : 0;
  const int sd = dir ? -1 : 1;
  float dv_n = to_f(DELTA[(rowbase + t) * 1024 + d]);
  float xv_n = XC[(rowbase + t) * 1024 + d];
  float res_n = X2[(rowbase + t) * 2048 + 1024 + d];
  float h0 = 0.f, h1 = 0.f, h2 = 0.f, h3 = 0.f;
  for (int step = 0; step < Nn; ++step) {
    const float dv = dv_n, xv = xv_n, res = res_n;
    const int tc = t;
    t += sd;
    if (step + 1 < Nn) {
      dv_n = to_f(DELTA[(rowbase + t) * 1024 + d]);
      xv_n = XC[(rowbase + t) * 1024 + d];
      res_n = X2[(rowbase + t) * 2048 + 1024 + d];
    }
    const float* bc = sBC + tc * 32;
    const float4 Bm = *(const float4*)(bc + sg * 4);
    const float4 Cm = *(const float4*)(bc + 16 + sg * 4);
    const float dx = dv * xv;
    h0 = __expf(dv * A_[0]) * h0 + dx * Bm.x;
    h1 = __expf(dv * A_[1]) * h1 + dx * Bm.y;
    h2 = __expf(dv * A_[2]) * h2 + dx * Bm.z;
    h3 = __expf(dv * A_[3]) * h3 + dx * Bm.w;
    float acc = h0 * Cm.x + h1 * Cm.y + h2 * Cm.z + h3 * Cm.w;
    acc += __shfl_xor(acc, 16, 64);
    acc += __shfl_xor(acc, 32, 64);
    if (sg == 0) {
      const float g = res / (1.f + __expf(-res));
      XC[(rowbase + tc) * 1024 + d] = (acc + xv * dp) * g;
    }
  }
}

// ---- LayerNorm (trusted R3) -----------------------------------------------
template <int MODE, typename TW>
__global__ __launch_bounds__(256) void ln_kernel(const int* __restrict__ flagp, int want,
                                                 const float* __restrict__ Z,
                                                 const float* __restrict__ Zadd,
                                                 const TW* __restrict__ g,
                                                 const TW* __restrict__ bb,
                                                 void* __restrict__ outp) {
  if (*flagp != want) return;
  const int row = blockIdx.x;
  const int tid = threadIdx.x;
  const float2* z = (const float2*)(Z + (size_t)row * Ll);
  float2 v = z[tid];
  if (MODE == 1) {
    const float2* za = (const float2*)(Zadd + (size_t)row * Ll);
    float2 a = za[tid];
    v.x += a.x;
    v.y += a.y;
  }
  float s = v.x + v.y, q = v.x * v.x + v.y * v.y;
#pragma unroll
  for (int o = 32; o > 0; o >>= 1) {
    s += __shfl_xor(s, o, 64);
    q += __shfl_xor(q, o, 64);
  }
  __shared__ float ss[4], qq[4];
  const int wv = tid >> 6, ln = tid & 63;
  if (ln == 0) { ss[wv] = s; qq[wv] = q; }
  __syncthreads();
  s = ss[0] + ss[1] + ss[2] + ss[3];
  q = qq[0] + qq[1] + qq[2] + qq[3];
  const float mean = s * (1.f / Ll);
  const float var = q * (1.f / Ll) - mean * mean;
  const float rs = rsqrtf(var + 1e-5f);
  const int c0 = tid * 2;
  const float o0 = (v.x - mean) * rs * to_f(g[c0]) + to_f(bb[c0]);
  const float o1 = (v.y - mean) * rs * to_f(g[c0 + 1]) + to_f(bb[c0 + 1]);
  if (MODE == 0) {
    float* out = (float*)outp;
    out[(size_t)row * Ll + c0] = o0;
    out[(size_t)row * Ll + c0 + 1] = o1;
  } else {
    TW* out = (TW*)outp;
    store_t(&out[(size_t)row * Ll + c0], o0);
    store_t(&out[(size_t)row * Ll + c0 + 1], o1);
  }
}

template <typename TW>
__global__ __launch_bounds__(256) void init_zbuf_kernel(const int* __restrict__ flagp, int want,
                                                        const TW* __restrict__ x,
                                                        float* __restrict__ ZB, int n) {
  if (*flagp != want) return;
  int i = blockIdx.x * 256 + threadIdx.x;
  if (i < n) ZB[i] = to_f(x[i]);
}

// ---- pipeline (dual-instantiated, flag-gated) -----------------------------
template <typename TW>
static void run_pipeline(void* const* d_in, void* d_out, const int* flagp, int want,
                         float* X2, float* XC, float* DBC, float* ZB, float* Y3,
                         hipStream_t stream) {
  const TW* x = (const TW*)d_in[0];
  const TW* in_w[2] = {(const TW*)d_in[1], (const TW*)d_in[10]};
  const TW* conv_w[2] = {(const TW*)d_in[2], (const TW*)d_in[11]};
  const TW* conv_b[2] = {(const TW*)d_in[3], (const TW*)d_in[12]};
  const TW* xproj_w[2] = {(const TW*)d_in[4], (const TW*)d_in[13]};
  const TW* dt_w[2] = {(const TW*)d_in[5], (const TW*)d_in[14]};
  const TW* dt_b[2] = {(const TW*)d_in[6], (const TW*)d_in[15]};
  const TW* A_log[2] = {(const TW*)d_in[7], (const TW*)d_in[16]};
  const TW* Dp[2] = {(const TW*)d_in[8], (const TW*)d_in[17]};
  const TW* out_w[2] = {(const TW*)d_in[9], (const TW*)d_in[18]};
  const TW* pu_w = (const TW*)d_in[19];
  const TW* pu_b = (const TW*)d_in[20];
  const TW* pl_w = (const TW*)d_in[21];
  const TW* pl_b = (const TW*)d_in[22];
  const TW* ln_g = (const TW*)d_in[23];
  const TW* ln_b = (const TW*)d_in[24];
  float* H1 = X2;            // alias: X2 dead after dir loop
  float* Z2 = XC;            // alias: XC dead after dir loop
  bf16* DELTAb = (bf16*)Y3;  // alias: Y3 (4 MB) dead during dir loop

  const dim3 blk(256);

  init_zbuf_kernel<TW><<<dim3((Mm * Ll + 255) / 256), blk, 0, stream>>>(flagp, want, x, ZB, Mm * Ll);

  for (int dir = 0; dir < 2; ++dir) {
    // X2 = x @ in_w^T  (2048x2048x512), grid 32x32 = 1024 blocks
    gemm_mfma<TW, TW, float, EPI_STORE><<<dim3(32, 32), blk, 0, stream>>>(
        flagp, want, x, Ll, in_w[dir], Ll, X2, 2048, (const TW*)nullptr, 2048, Ll);
    conv_silu_kernel<TW><<<dim3(Mm, 4), blk, 0, stream>>>(
        flagp, want, X2, conv_w[dir], conv_b[dir], XC, dir);
    // dbc = xc @ xproj_w^T  (2048x96x1024), split-K=4 -> 256 blocks, atomic
    zero_kernel<<<dim3(192), blk, 0, stream>>>((float4*)DBC, Mm * 96 / 4);
    gemm_mfma<float, TW, float, EPI_ATOMIC><<<dim3(2, 32, 4), blk, 0, stream>>>(
        flagp, want, XC, Dd, xproj_w[dir], Dd, DBC, 96, (const TW*)nullptr, 96, 256);
    // DELTA = softplus(dt @ dt_w^T + dt_b)  (2048x1024x64), grid 16x32 = 512
    gemm_mfma<float, TW, bf16, EPI_BIAS_SOFTPLUS><<<dim3(16, 32), blk, 0, stream>>>(
        flagp, want, DBC, 96, dt_w[dir], Rr, DELTAb, 1024, dt_b[dir], 1024, Rr);
    // selective scan + gating -> YG in place over XC
    scan_gate_kernel<TW><<<dim3(Bb, Dd / 64), blk, 0, stream>>>(
        flagp, want, DBC, XC, X2, DELTAb, A_log[dir], Dp[dir], dir);
    // ZB += YG @ out_w^T  (2048x512x1024), grid 8x32 = 256
    gemm_mfma<float, TW, float, EPI_ADD><<<dim3(8, 32), blk, 0, stream>>>(
        flagp, want, XC, Dd, out_w[dir], Dd, ZB, Ll, (const TW*)nullptr, Ll, Dd);
  }

  ln_kernel<0, TW><<<dim3(Mm), blk, 0, stream>>>(flagp, want, ZB, nullptr, ln_g, ln_b, (void*)Y3);
  // H1 = relu(y3 @ pu_w^T + pu_b)  (2048x2048x512), grid 32x32
  gemm_mfma<float, TW, float, EPI_BIAS_RELU><<<dim3(32, 32), blk, 0, stream>>>(
      flagp, want, Y3, Ll, pu_w, Ll, H1, Hh, pu_b, Hh, Ll);
  // Z2 = H1 @ pl_w^T + pl_b  (2048x512x2048), grid 8x32
  gemm_mfma<float, TW, float, EPI_BIAS><<<dim3(8, 32), blk, 0, stream>>>(
      flagp, want, H1, Hh, pl_w, Hh, Z2, Ll, pl_b, Ll, Hh);
  ln_kernel<1, TW><<<dim3(Mm), blk, 0, stream>>>(flagp, want, Z2, Y3, ln_g, ln_b, d_out);
}

extern "C" void kernel_launch(void* const* d_in, const int* in_sizes, int n_in, void* d_out,
                              int out_size, void* d_ws, size_t ws_size, hipStream_t stream) {
  char* ws = (char*)d_ws;
  int* flags = (int*)ws;
  float* X2 = (float*)(ws + 256);
  float* XC = X2 + (size_t)Mm * 2048;
  float* DBC = XC + (size_t)Mm * 1024;
  float* ZB = DBC + (size_t)Mm * 96;
  float* Y3 = ZB + (size_t)Mm * 512;
  size_t needed = 256 + sizeof(float) * ((size_t)Mm * 2048 + Mm * 1024 + Mm * 96 + Mm * 512 + Mm * 512);
  if (ws_size < needed) return;

  const dim3 blk(256);
  sniff_kernel<<<dim3(1), blk, 0, stream>>>((const unsigned short*)d_in[0], flags);

  run_pipeline<bf16>(d_in, d_out, flags, 1, X2, XC, DBC, ZB, Y3, stream);
  run_pipeline<float>(d_in, d_out, flags, 0, X2, XC, DBC, ZB, Y3, stream);

  (void)in_sizes; (void)n_in; (void)out_size;
}

// Round 11
// 517.408 us; speedup vs baseline: 1.0076x; 1.0076x over previous
//
#include <hip/hip_runtime.h>
#include <hip/hip_bf16.h>
#include <cstdint>

typedef __hip_bfloat16 bf16;

constexpr int Bb = 16, Nn = 128, Ll = 512, Dd = 1024, Ss = 16, Rr = 64, Hh = 2048;
constexpr int Mm = Bb * Nn; // 2048 rows

using bf16x8 = __attribute__((ext_vector_type(8))) __bf16;
using f32x4  = __attribute__((ext_vector_type(4))) float;

__device__ __forceinline__ float to_f(float x) { return x; }
__device__ __forceinline__ float to_f(bf16 x) { return __bfloat162float(x); }
__device__ __forceinline__ void store_t(float* p, float v) { *p = v; }
__device__ __forceinline__ void store_t(bf16* p, float v) { *p = __float2bfloat16(v); }
__device__ __forceinline__ __bf16 cvt1(float x) {
  bf16 h = __float2bfloat16(x);
  return *reinterpret_cast<__bf16*>(&h);
}
__device__ __forceinline__ bf16x8 load8(const bf16* p) { return *(const bf16x8*)p; }
__device__ __forceinline__ bf16x8 load8(const float* p) {
  float4 a = *(const float4*)p;
  float4 b = *(const float4*)(p + 4);
  bf16x8 r;
  r[0] = cvt1(a.x); r[1] = cvt1(a.y); r[2] = cvt1(a.z); r[3] = cvt1(a.w);
  r[4] = cvt1(b.x); r[5] = cvt1(b.y); r[6] = cvt1(b.z); r[7] = cvt1(b.w);
  return r;
}

enum { EPI_STORE = 0, EPI_BIAS_RELU = 1, EPI_ADD = 3, EPI_BIAS = 4, EPI_BIAS_SOFTPLUS = 5,
       EPI_ATOMIC = 6 };

// ---- dtype sniffer --------------------------------------------------------
__global__ void sniff_kernel(const unsigned short* __restrict__ xs, int* __restrict__ flags) {
  const int tid = threadIdx.x;
  int cnt = 0;
  for (int j = 0; j < 64; ++j) {
    int i = tid + j * 256;
    unsigned short u = xs[(size_t)i * 64];
    bf16 h = *reinterpret_cast<bf16*>(&u);
    float v = __bfloat162float(h);
    float a = fabsf(v);
    if (v == 0.f || (a > 0.0009765625f && a < 16.f)) ++cnt;
  }
  __shared__ int sc[256];
  sc[tid] = cnt;
  __syncthreads();
  for (int o = 128; o > 0; o >>= 1) {
    if (tid < o) sc[tid] += sc[tid + o];
    __syncthreads();
  }
  if (tid == 0) flags[0] = (sc[0] > 8192) ? 1 : 0; // 1 = bf16, 0 = f32
}

// ---- MFMA GEMM (R8/R10 green core): 64x64 tile, BK=64, split-K via grid.z --
constexpr int LDT2 = 72; // row stride el: 144 B, 16B-aligned
template <typename TA, typename TW, typename TC, int EPI>
__global__ __launch_bounds__(256) void gemm_mfma(const int* __restrict__ flagp, int want,
                                                 const TA* __restrict__ A, int lda,
                                                 const TW* __restrict__ Bw, int ldb,
                                                 TC* __restrict__ C, int ldc,
                                                 const TW* __restrict__ bias,
                                                 int N, int Kchunk) {
  if (*flagp != want) return;
  __shared__ __align__(16) __bf16 As[64 * LDT2];
  __shared__ __align__(16) __bf16 Bs[64 * LDT2];
  const int tid = threadIdx.x;
  const int wave = tid >> 6, lane = tid & 63;
  const int quad = lane >> 4, l16 = lane & 15;
  const int wm = wave & 1, wn = wave >> 1;
  int bx = blockIdx.x, by = blockIdx.y;
  const int gx = gridDim.x, gy = gridDim.y;
  if ((gx & 7) == 0) { // XCD swizzle (bijection; neutral in R10 but green)
    int id = bx + gx * by;
    int xcd = id & 7, sl = id >> 3;
    by = sl % gy;
    bx = (sl / gy) * 8 + xcd;
  }
  const int m0 = by * 64, n0 = bx * 64;
  const int kb = blockIdx.z * Kchunk;
  const int srow = tid >> 3;      // 0..31
  const int scol = (tid & 7) * 8; // 0..56
  f32x4 acc[2][2] = {};
  for (int k0 = kb; k0 < kb + Kchunk; k0 += 64) {
#pragma unroll
    for (int h = 0; h < 2; ++h) {
      int r = srow + h * 32;
      *(bf16x8*)(&As[r * LDT2 + scol]) = load8(A + (size_t)(m0 + r) * lda + k0 + scol);
      int rb = n0 + r;
      rb = rb < N ? rb : N - 1; // clamp (ragged N); garbage cols masked in epilogue
      *(bf16x8*)(&Bs[r * LDT2 + scol]) = load8(Bw + (size_t)rb * ldb + k0 + scol);
    }
    __syncthreads();
#pragma unroll
    for (int kk = 0; kk < 2; ++kk) {
      bf16x8 af[2], bfr[2];
#pragma unroll
      for (int i = 0; i < 2; ++i)
        af[i] = *(const bf16x8*)(&As[(wm * 32 + i * 16 + l16) * LDT2 + kk * 32 + quad * 8]);
#pragma unroll
      for (int j = 0; j < 2; ++j)
        bfr[j] = *(const bf16x8*)(&Bs[(wn * 32 + j * 16 + l16) * LDT2 + kk * 32 + quad * 8]);
#pragma unroll
      for (int i = 0; i < 2; ++i)
#pragma unroll
        for (int j = 0; j < 2; ++j)
          acc[i][j] = __builtin_amdgcn_mfma_f32_16x16x32_bf16(af[i], bfr[j], acc[i][j], 0, 0, 0);
    }
    __syncthreads();
  }
#pragma unroll
  for (int i = 0; i < 2; ++i) {
#pragma unroll
    for (int j = 0; j < 2; ++j) {
      const int col = n0 + wn * 32 + j * 16 + l16;
      if (col >= N) continue;
      float bv = 0.f;
      if (EPI == EPI_BIAS_RELU || EPI == EPI_BIAS || EPI == EPI_BIAS_SOFTPLUS) bv = to_f(bias[col]);
#pragma unroll
      for (int r = 0; r < 4; ++r) {
        const int row = m0 + wm * 32 + i * 16 + quad * 4 + r;
        size_t idx = (size_t)row * ldc + col;
        float v = acc[i][j][r];
        if (EPI == EPI_STORE) store_t(&C[idx], v);
        else if (EPI == EPI_BIAS_RELU) { v += bv; store_t(&C[idx], v > 0.f ? v : 0.f); }
        else if (EPI == EPI_ADD) ((float*)C)[idx] += v;        // TC=float only
        else if (EPI == EPI_BIAS) store_t(&C[idx], v + bv);
        else if (EPI == EPI_BIAS_SOFTPLUS) {
          v += bv;
          store_t(&C[idx], (v > 20.f) ? v : log1pf(__expf(v)));
        } else if (EPI == EPI_ATOMIC) {
          atomicAdd((float*)&C[idx], v);                        // TC=float only
        }
      }
    }
  }
}

// ---- helpers --------------------------------------------------------------
__global__ __launch_bounds__(256) void zero_kernel(float4* __restrict__ p, int n4) {
  int i = blockIdx.x * 256 + threadIdx.x;
  if (i < n4) p[i] = float4{0.f, 0.f, 0.f, 0.f};
}

// fill Z[row][c] = bias[c]  (ld = ncols)
template <typename TW>
__global__ __launch_bounds__(256) void bias_fill_kernel(const int* __restrict__ flagp, int want,
                                                        const TW* __restrict__ bias,
                                                        float* __restrict__ Z, int n, int cmask) {
  if (*flagp != want) return;
  int i = blockIdx.x * 256 + threadIdx.x;
  if (i < n) Z[i] = to_f(bias[i & cmask]);
}

// in-place H = relu(H + bias[col])
template <typename TW>
__global__ __launch_bounds__(256) void bias_relu_kernel(const int* __restrict__ flagp, int want,
                                                        const TW* __restrict__ bias,
                                                        float* __restrict__ H, int n, int cmask) {
  if (*flagp != want) return;
  int i = blockIdx.x * 256 + threadIdx.x;
  if (i < n) {
    float v = H[i] + to_f(bias[i & cmask]);
    H[i] = v > 0.f ? v : 0.f;
  }
}

// ---- depthwise conv + SiLU (trusted R3) -----------------------------------
template <typename TW>
__global__ __launch_bounds__(256) void conv_silu_kernel(const int* __restrict__ flagp, int want,
                                                        const float* __restrict__ X2,
                                                        const TW* __restrict__ cw,
                                                        const TW* __restrict__ cb,
                                                        float* __restrict__ XC, int dir) {
  if (*flagp != want) return;
  const int d = blockIdx.y * 256 + threadIdx.x;
  const int m = blockIdx.x;
  const int t = m & (Nn - 1);
  float w0 = to_f(cw[d * 4 + 0]), w1 = to_f(cw[d * 4 + 1]);
  float w2 = to_f(cw[d * 4 + 2]), w3 = to_f(cw[d * 4 + 3]);
  float a = to_f(cb[d]);
  if (dir == 0) {
    if (t >= 3) a += w0 * X2[(size_t)(m - 3) * 2048 + d];
    if (t >= 2) a += w1 * X2[(size_t)(m - 2) * 2048 + d];
    if (t >= 1) a += w2 * X2[(size_t)(m - 1) * 2048 + d];
    a += w3 * X2[(size_t)m * 2048 + d];
  } else {
    if (t + 3 < Nn) a += w0 * X2[(size_t)(m + 3) * 2048 + d];
    if (t + 2 < Nn) a += w1 * X2[(size_t)(m + 2) * 2048 + d];
    if (t + 1 < Nn) a += w2 * X2[(size_t)(m + 1) * 2048 + d];
    a += w3 * X2[(size_t)m * 2048 + d];
  }
  XC[(size_t)m * 1024 + d] = a / (1.f + __expf(-a));
}

// ---- selective scan (R7, trusted): DELTA precomputed, Bm/Cm LDS, prefetch --
template <typename TW>
__global__ __launch_bounds__(256) void scan_gate_kernel(
    const int* __restrict__ flagp, int want,
    const float* __restrict__ DBC, float* __restrict__ XC, const float* __restrict__ X2,
    const bf16* __restrict__ DELTA,
    const TW* __restrict__ A_log, const TW* __restrict__ Dp, int dir) {
  if (*flagp != want) return;
  __shared__ __align__(16) float sBC[Nn * 32]; // Bm|Cm per t: 16 KB
  const int b = blockIdx.x;
  const int dblk = blockIdx.y;
  const int tid = threadIdx.x;
  {
    const float* src = DBC + (size_t)b * Nn * 96;
#pragma unroll
    for (int k2 = 0; k2 < 16; ++k2) {
      int f = tid + k2 * 256;
      int r = f >> 5, c = f & 31;
      sBC[f] = src[r * 96 + 64 + c];
    }
  }
  __syncthreads();
  const int lane = tid & 63, wave = tid >> 6;
  const int dl = lane & 15, sg = lane >> 4;
  const int d = dblk * 64 + wave * 16 + dl;
  float A_[4];
#pragma unroll
  for (int j = 0; j < 4; ++j) A_[j] = -__expf(to_f(A_log[d * Ss + sg * 4 + j]));
  const float dp = to_f(Dp[d]);
  const size_t rowbase = (size_t)b * Nn;
  int t = dir ? (Nn - 1) : 0;
  const int sd = dir ? -1 : 1;
  float dv_n = to_f(DELTA[(rowbase + t) * 1024 + d]);
  float xv_n = XC[(rowbase + t) * 1024 + d];
  float res_n = X2[(rowbase + t) * 2048 + 1024 + d];
  float h0 = 0.f, h1 = 0.f, h2 = 0.f, h3 = 0.f;
  for (int step = 0; step < Nn; ++step) {
    const float dv = dv_n, xv = xv_n, res = res_n;
    const int tc = t;
    t += sd;
    if (step + 1 < Nn) {
      dv_n = to_f(DELTA[(rowbase + t) * 1024 + d]);
      xv_n = XC[(rowbase + t) * 1024 + d];
      res_n = X2[(rowbase + t) * 2048 + 1024 + d];
    }
    const float* bc = sBC + tc * 32;
    const float4 Bm = *(const float4*)(bc + sg * 4);
    const float4 Cm = *(const float4*)(bc + 16 + sg * 4);
    const float dx = dv * xv;
    h0 = __expf(dv * A_[0]) * h0 + dx * Bm.x;
    h1 = __expf(dv * A_[1]) * h1 + dx * Bm.y;
    h2 = __expf(dv * A_[2]) * h2 + dx * Bm.z;
    h3 = __expf(dv * A_[3]) * h3 + dx * Bm.w;
    float acc = h0 * Cm.x + h1 * Cm.y + h2 * Cm.z + h3 * Cm.w;
    acc += __shfl_xor(acc, 16, 64);
    acc += __shfl_xor(acc, 32, 64);
    if (sg == 0) {
      const float g = res / (1.f + __expf(-res));
      XC[(rowbase + tc) * 1024 + d] = (acc + xv * dp) * g;
    }
  }
}

// ---- LayerNorm (trusted R3) -----------------------------------------------
template <int MODE, typename TW>
__global__ __launch_bounds__(256) void ln_kernel(const int* __restrict__ flagp, int want,
                                                 const float* __restrict__ Z,
                                                 const float* __restrict__ Zadd,
                                                 const TW* __restrict__ g,
                                                 const TW* __restrict__ bb,
                                                 void* __restrict__ outp) {
  if (*flagp != want) return;
  const int row = blockIdx.x;
  const int tid = threadIdx.x;
  const float2* z = (const float2*)(Z + (size_t)row * Ll);
  float2 v = z[tid];
  if (MODE == 1) {
    const float2* za = (const float2*)(Zadd + (size_t)row * Ll);
    float2 a = za[tid];
    v.x += a.x;
    v.y += a.y;
  }
  float s = v.x + v.y, q = v.x * v.x + v.y * v.y;
#pragma unroll
  for (int o = 32; o > 0; o >>= 1) {
    s += __shfl_xor(s, o, 64);
    q += __shfl_xor(q, o, 64);
  }
  __shared__ float ss[4], qq[4];
  const int wv = tid >> 6, ln = tid & 63;
  if (ln == 0) { ss[wv] = s; qq[wv] = q; }
  __syncthreads();
  s = ss[0] + ss[1] + ss[2] + ss[3];
  q = qq[0] + qq[1] + qq[2] + qq[3];
  const float mean = s * (1.f / Ll);
  const float var = q * (1.f / Ll) - mean * mean;
  const float rs = rsqrtf(var + 1e-5f);
  const int c0 = tid * 2;
  const float o0 = (v.x - mean) * rs * to_f(g[c0]) + to_f(bb[c0]);
  const float o1 = (v.y - mean) * rs * to_f(g[c0 + 1]) + to_f(bb[c0 + 1]);
  if (MODE == 0) {
    float* out = (float*)outp;
    out[(size_t)row * Ll + c0] = o0;
    out[(size_t)row * Ll + c0 + 1] = o1;
  } else {
    TW* out = (TW*)outp;
    store_t(&out[(size_t)row * Ll + c0], o0);
    store_t(&out[(size_t)row * Ll + c0 + 1], o1);
  }
}

template <typename TW>
__global__ __launch_bounds__(256) void init_zbuf_kernel(const int* __restrict__ flagp, int want,
                                                        const TW* __restrict__ x,
                                                        float* __restrict__ ZB, int n) {
  if (*flagp != want) return;
  int i = blockIdx.x * 256 + threadIdx.x;
  if (i < n) ZB[i] = to_f(x[i]);
}

// ---- pipeline (dual-instantiated, flag-gated) -----------------------------
template <typename TW>
static void run_pipeline(void* const* d_in, void* d_out, const int* flagp, int want,
                         float* X2, float* XC, float* DBC, float* ZB, float* Y3,
                         hipStream_t stream) {
  const TW* x = (const TW*)d_in[0];
  const TW* in_w[2] = {(const TW*)d_in[1], (const TW*)d_in[10]};
  const TW* conv_w[2] = {(const TW*)d_in[2], (const TW*)d_in[11]};
  const TW* conv_b[2] = {(const TW*)d_in[3], (const TW*)d_in[12]};
  const TW* xproj_w[2] = {(const TW*)d_in[4], (const TW*)d_in[13]};
  const TW* dt_w[2] = {(const TW*)d_in[5], (const TW*)d_in[14]};
  const TW* dt_b[2] = {(const TW*)d_in[6], (const TW*)d_in[15]};
  const TW* A_log[2] = {(const TW*)d_in[7], (const TW*)d_in[16]};
  const TW* Dp[2] = {(const TW*)d_in[8], (const TW*)d_in[17]};
  const TW* out_w[2] = {(const TW*)d_in[9], (const TW*)d_in[18]};
  const TW* pu_w = (const TW*)d_in[19];
  const TW* pu_b = (const TW*)d_in[20];
  const TW* pl_w = (const TW*)d_in[21];
  const TW* pl_b = (const TW*)d_in[22];
  const TW* ln_g = (const TW*)d_in[23];
  const TW* ln_b = (const TW*)d_in[24];
  float* H1 = X2;            // alias: X2 dead after dir loop
  float* Z2 = XC;            // alias: XC dead after dir loop
  bf16* DELTAb = (bf16*)Y3;  // alias: Y3 (4 MB) dead during dir loop

  const dim3 blk(256);

  init_zbuf_kernel<TW><<<dim3((Mm * Ll + 255) / 256), blk, 0, stream>>>(flagp, want, x, ZB, Mm * Ll);

  for (int dir = 0; dir < 2; ++dir) {
    // X2 = x @ in_w^T  (2048x2048x512), grid 32x32 = 1024 blocks
    gemm_mfma<TW, TW, float, EPI_STORE><<<dim3(32, 32), blk, 0, stream>>>(
        flagp, want, x, Ll, in_w[dir], Ll, X2, 2048, (const TW*)nullptr, 2048, Ll);
    conv_silu_kernel<TW><<<dim3(Mm, 4), blk, 0, stream>>>(
        flagp, want, X2, conv_w[dir], conv_b[dir], XC, dir);
    // dbc = xc @ xproj_w^T  (2048x96x1024), split-K=4 -> 256 blocks, atomic
    zero_kernel<<<dim3(192), blk, 0, stream>>>((float4*)DBC, Mm * 96 / 4);
    gemm_mfma<float, TW, float, EPI_ATOMIC><<<dim3(2, 32, 4), blk, 0, stream>>>(
        flagp, want, XC, Dd, xproj_w[dir], Dd, DBC, 96, (const TW*)nullptr, 96, 256);
    // DELTA = softplus(dt @ dt_w^T + dt_b)  (2048x1024x64), grid 16x32 = 512
    gemm_mfma<float, TW, bf16, EPI_BIAS_SOFTPLUS><<<dim3(16, 32), blk, 0, stream>>>(
        flagp, want, DBC, 96, dt_w[dir], Rr, DELTAb, 1024, dt_b[dir], 1024, Rr);
    // selective scan + gating -> YG in place over XC
    scan_gate_kernel<TW><<<dim3(Bb, Dd / 64), blk, 0, stream>>>(
        flagp, want, DBC, XC, X2, DELTAb, A_log[dir], Dp[dir], dir);
    // ZB += YG @ out_w^T  (2048x512x1024), split-K=4 -> (8,32,4) = 1024 blocks
    gemm_mfma<float, TW, float, EPI_ATOMIC><<<dim3(8, 32, 4), blk, 0, stream>>>(
        flagp, want, XC, Dd, out_w[dir], Dd, ZB, Ll, (const TW*)nullptr, Ll, 256);
  }

  // H1raw = 0; y3 = LN(ZB)
  zero_kernel<<<dim3(Mm * Hh / 4 / 256), blk, 0, stream>>>((float4*)H1, Mm * Hh / 4);
  ln_kernel<0, TW><<<dim3(Mm), blk, 0, stream>>>(flagp, want, ZB, nullptr, ln_g, ln_b, (void*)Y3);
  // H1raw += y3 @ pu_w^T  (split-K=2 -> (32,32,2) = 2048 blocks, atomic)
  gemm_mfma<float, TW, float, EPI_ATOMIC><<<dim3(32, 32, 2), blk, 0, stream>>>(
      flagp, want, Y3, Ll, pu_w, Ll, H1, Hh, (const TW*)nullptr, Hh, 256);
  // H1 = relu(H1raw + pu_b)
  bias_relu_kernel<TW><<<dim3(Mm * Hh / 256), blk, 0, stream>>>(
      flagp, want, pu_b, H1, Mm * Hh, Hh - 1);
  // Z2 = pl_b; Z2 += H1 @ pl_w^T  (split-K=4 -> (8,32,4) = 1024 blocks, atomic)
  bias_fill_kernel<TW><<<dim3(Mm * Ll / 256), blk, 0, stream>>>(
      flagp, want, pl_b, Z2, Mm * Ll, Ll - 1);
  gemm_mfma<float, TW, float, EPI_ATOMIC><<<dim3(8, 32, 4), blk, 0, stream>>>(
      flagp, want, H1, Hh, pl_w, Hh, Z2, Ll, (const TW*)nullptr, Ll, 512);
  // out = bf16(LN(Z2 + y3))
  ln_kernel<1, TW><<<dim3(Mm), blk, 0, stream>>>(flagp, want, Z2, Y3, ln_g, ln_b, d_out);
}

extern "C" void kernel_launch(void* const* d_in, const int* in_sizes, int n_in, void* d_out,
                              int out_size, void* d_ws, size_t ws_size, hipStream_t stream) {
  char* ws = (char*)d_ws;
  int* flags = (int*)ws;
  float* X2 = (float*)(ws + 256);
  float* XC = X2 + (size_t)Mm * 2048;
  float* DBC = XC + (size_t)Mm * 1024;
  float* ZB = DBC + (size_t)Mm * 96;
  float* Y3 = ZB + (size_t)Mm * 512;
  size_t needed = 256 + sizeof(float) * ((size_t)Mm * 2048 + Mm * 1024 + Mm * 96 + Mm * 512 + Mm * 512);
  if (ws_size < needed) return;

  const dim3 blk(256);
  sniff_kernel<<<dim3(1), blk, 0, stream>>>((const unsigned short*)d_in[0], flags);

  run_pipeline<bf16>(d_in, d_out, flags, 1, X2, XC, DBC, ZB, Y3, stream);
  run_pipeline<float>(d_in, d_out, flags, 0, X2, XC, DBC, ZB, Y3, stream);

  (void)in_sizes; (void)n_in; (void)out_size;
}

// Round 12
// 503.617 us; speedup vs baseline: 1.0352x; 1.0274x over previous
//
#include <hip/hip_runtime.h>
#include <hip/hip_bf16.h>
#include <cstdint>

typedef __hip_bfloat16 bf16;

constexpr int Bb = 16, Nn = 128, Ll = 512, Dd = 1024, Ss = 16, Rr = 64, Hh = 2048;
constexpr int Mm = Bb * Nn; // 2048 rows

using bf16x8 = __attribute__((ext_vector_type(8))) __bf16;
using bf16x4 = __attribute__((ext_vector_type(4))) __bf16;
using f32x4  = __attribute__((ext_vector_type(4))) float;

__device__ __forceinline__ float to_f(float x) { return x; }
__device__ __forceinline__ float to_f(bf16 x) { return __bfloat162float(x); }
__device__ __forceinline__ void store_t(float* p, float v) { *p = v; }
__device__ __forceinline__ void store_t(bf16* p, float v) { *p = __float2bfloat16(v); }
__device__ __forceinline__ __bf16 cvt1(float x) {
  bf16 h = __float2bfloat16(x);
  return *reinterpret_cast<__bf16*>(&h);
}
__device__ __forceinline__ float bfraw_to_f(__bf16 x) {
  bf16 h = *reinterpret_cast<bf16*>(&x);
  return __bfloat162float(h);
}
__device__ __forceinline__ bf16x8 load8(const bf16* p) { return *(const bf16x8*)p; }
__device__ __forceinline__ bf16x8 load8(const float* p) {
  float4 a = *(const float4*)p;
  float4 b = *(const float4*)(p + 4);
  bf16x8 r;
  r[0] = cvt1(a.x); r[1] = cvt1(a.y); r[2] = cvt1(a.z); r[3] = cvt1(a.w);
  r[4] = cvt1(b.x); r[5] = cvt1(b.y); r[6] = cvt1(b.z); r[7] = cvt1(b.w);
  return r;
}

enum { EPI_STORE = 0, EPI_BIAS_RELU = 1, EPI_ADD = 3, EPI_BIAS = 4, EPI_BIAS_SOFTPLUS = 5,
       EPI_ATOMIC = 6 };

// ---- dtype sniffer --------------------------------------------------------
__global__ void sniff_kernel(const unsigned short* __restrict__ xs, int* __restrict__ flags) {
  const int tid = threadIdx.x;
  int cnt = 0;
  for (int j = 0; j < 64; ++j) {
    int i = tid + j * 256;
    unsigned short u = xs[(size_t)i * 64];
    bf16 h = *reinterpret_cast<bf16*>(&u);
    float v = __bfloat162float(h);
    float a = fabsf(v);
    if (v == 0.f || (a > 0.0009765625f && a < 16.f)) ++cnt;
  }
  __shared__ int sc[256];
  sc[tid] = cnt;
  __syncthreads();
  for (int o = 128; o > 0; o >>= 1) {
    if (tid < o) sc[tid] += sc[tid + o];
    __syncthreads();
  }
  if (tid == 0) flags[0] = (sc[0] > 8192) ? 1 : 0; // 1 = bf16, 0 = f32
}

// ---- MFMA GEMM (R8/R10/R11 green core): 64x64 tile, BK=64, split-K grid.z --
constexpr int LDT2 = 72; // row stride el: 144 B, 16B-aligned
template <typename TA, typename TW, typename TC, int EPI>
__global__ __launch_bounds__(256) void gemm_mfma(const int* __restrict__ flagp, int want,
                                                 const TA* __restrict__ A, int lda,
                                                 const TW* __restrict__ Bw, int ldb,
                                                 TC* __restrict__ C, int ldc,
                                                 const TW* __restrict__ bias,
                                                 int N, int Kchunk) {
  if (*flagp != want) return;
  __shared__ __align__(16) __bf16 As[64 * LDT2];
  __shared__ __align__(16) __bf16 Bs[64 * LDT2];
  const int tid = threadIdx.x;
  const int wave = tid >> 6, lane = tid & 63;
  const int quad = lane >> 4, l16 = lane & 15;
  const int wm = wave & 1, wn = wave >> 1;
  int bx = blockIdx.x, by = blockIdx.y;
  const int gx = gridDim.x, gy = gridDim.y;
  if ((gx & 7) == 0) { // XCD swizzle (bijection)
    int id = bx + gx * by;
    int xcd = id & 7, sl = id >> 3;
    by = sl % gy;
    bx = (sl / gy) * 8 + xcd;
  }
  const int m0 = by * 64, n0 = bx * 64;
  const int kb = blockIdx.z * Kchunk;
  const int srow = tid >> 3;      // 0..31
  const int scol = (tid & 7) * 8; // 0..56
  f32x4 acc[2][2] = {};
  for (int k0 = kb; k0 < kb + Kchunk; k0 += 64) {
#pragma unroll
    for (int h = 0; h < 2; ++h) {
      int r = srow + h * 32;
      *(bf16x8*)(&As[r * LDT2 + scol]) = load8(A + (size_t)(m0 + r) * lda + k0 + scol);
      int rb = n0 + r;
      rb = rb < N ? rb : N - 1; // clamp (ragged N); garbage cols masked in epilogue
      *(bf16x8*)(&Bs[r * LDT2 + scol]) = load8(Bw + (size_t)rb * ldb + k0 + scol);
    }
    __syncthreads();
#pragma unroll
    for (int kk = 0; kk < 2; ++kk) {
      bf16x8 af[2], bfr[2];
#pragma unroll
      for (int i = 0; i < 2; ++i)
        af[i] = *(const bf16x8*)(&As[(wm * 32 + i * 16 + l16) * LDT2 + kk * 32 + quad * 8]);
#pragma unroll
      for (int j = 0; j < 2; ++j)
        bfr[j] = *(const bf16x8*)(&Bs[(wn * 32 + j * 16 + l16) * LDT2 + kk * 32 + quad * 8]);
#pragma unroll
      for (int i = 0; i < 2; ++i)
#pragma unroll
        for (int j = 0; j < 2; ++j)
          acc[i][j] = __builtin_amdgcn_mfma_f32_16x16x32_bf16(af[i], bfr[j], acc[i][j], 0, 0, 0);
    }
    __syncthreads();
  }
#pragma unroll
  for (int i = 0; i < 2; ++i) {
#pragma unroll
    for (int j = 0; j < 2; ++j) {
      const int col = n0 + wn * 32 + j * 16 + l16;
      if (col >= N) continue;
      float bv = 0.f;
      if (EPI == EPI_BIAS_RELU || EPI == EPI_BIAS || EPI == EPI_BIAS_SOFTPLUS) bv = to_f(bias[col]);
#pragma unroll
      for (int r = 0; r < 4; ++r) {
        const int row = m0 + wm * 32 + i * 16 + quad * 4 + r;
        size_t idx = (size_t)row * ldc + col;
        float v = acc[i][j][r];
        if (EPI == EPI_STORE) store_t(&C[idx], v);
        else if (EPI == EPI_BIAS_RELU) { v += bv; store_t(&C[idx], v > 0.f ? v : 0.f); }
        else if (EPI == EPI_ADD) ((float*)C)[idx] += v;        // TC=float only
        else if (EPI == EPI_BIAS) store_t(&C[idx], v + bv);
        else if (EPI == EPI_BIAS_SOFTPLUS) {
          v += bv;
          store_t(&C[idx], (v > 20.f) ? v : log1pf(__expf(v)));
        } else if (EPI == EPI_ATOMIC) {
          atomicAdd((float*)&C[idx], v);                        // TC=float only
        }
      }
    }
  }
}

// ---- helpers --------------------------------------------------------------
__global__ __launch_bounds__(256) void zero_kernel(float4* __restrict__ p, int n4) {
  int i = blockIdx.x * 256 + threadIdx.x;
  if (i < n4) p[i] = float4{0.f, 0.f, 0.f, 0.f};
}

template <typename TW>
__global__ __launch_bounds__(256) void bias_fill_kernel(const int* __restrict__ flagp, int want,
                                                        const TW* __restrict__ bias,
                                                        float* __restrict__ Z, int n, int cmask) {
  if (*flagp != want) return;
  int i = blockIdx.x * 256 + threadIdx.x;
  if (i < n) Z[i] = to_f(bias[i & cmask]);
}

template <typename TW>
__global__ __launch_bounds__(256) void bias_relu_kernel(const int* __restrict__ flagp, int want,
                                                        const TW* __restrict__ bias,
                                                        float* __restrict__ H, int n, int cmask) {
  if (*flagp != want) return;
  int i = blockIdx.x * 256 + threadIdx.x;
  if (i < n) {
    float v = H[i] + to_f(bias[i & cmask]);
    H[i] = v > 0.f ? v : 0.f;
  }
}

// ---- depthwise conv + SiLU (trusted R3) -----------------------------------
template <typename TW>
__global__ __launch_bounds__(256) void conv_silu_kernel(const int* __restrict__ flagp, int want,
                                                        const float* __restrict__ X2,
                                                        const TW* __restrict__ cw,
                                                        const TW* __restrict__ cb,
                                                        float* __restrict__ XC, int dir) {
  if (*flagp != want) return;
  const int d = blockIdx.y * 256 + threadIdx.x;
  const int m = blockIdx.x;
  const int t = m & (Nn - 1);
  float w0 = to_f(cw[d * 4 + 0]), w1 = to_f(cw[d * 4 + 1]);
  float w2 = to_f(cw[d * 4 + 2]), w3 = to_f(cw[d * 4 + 3]);
  float a = to_f(cb[d]);
  if (dir == 0) {
    if (t >= 3) a += w0 * X2[(size_t)(m - 3) * 2048 + d];
    if (t >= 2) a += w1 * X2[(size_t)(m - 2) * 2048 + d];
    if (t >= 1) a += w2 * X2[(size_t)(m - 1) * 2048 + d];
    a += w3 * X2[(size_t)m * 2048 + d];
  } else {
    if (t + 3 < Nn) a += w0 * X2[(size_t)(m + 3) * 2048 + d];
    if (t + 2 < Nn) a += w1 * X2[(size_t)(m + 2) * 2048 + d];
    if (t + 1 < Nn) a += w2 * X2[(size_t)(m + 1) * 2048 + d];
    a += w3 * X2[(size_t)m * 2048 + d];
  }
  XC[(size_t)m * 1024 + d] = a / (1.f + __expf(-a));
}

// ---- selective scan v3: full working set staged in 64 KB LDS --------------
// Grid (B=16, D/64=16), 256 thr (4 waves). Per block: all 128 steps' data for
// its 64 d's. The 128-step recurrence then runs entirely from LDS (serial
// chain = mul -> exp -> fma, ~25 cyc/step) instead of one global-load latency
// per step (R11: 390 ns/step).
template <typename TW>
__global__ __launch_bounds__(256) void scan_gate_kernel(
    const int* __restrict__ flagp, int want,
    const float* __restrict__ DBC, float* __restrict__ XC, const float* __restrict__ X2,
    const bf16* __restrict__ DELTA,
    const TW* __restrict__ A_log, const TW* __restrict__ Dp, int dir) {
  if (*flagp != want) return;
  __shared__ __align__(16) float sBC[Nn * 32];   // Bm|Cm per t (f32)   16 KB
  __shared__ __align__(16) __bf16 sD[Nn * 64];   // delta               16 KB
  __shared__ __align__(16) __bf16 sX[Nn * 64];   // xc                  16 KB
  __shared__ __align__(16) __bf16 sR[Nn * 64];   // res                 16 KB
  const int b = blockIdx.x;
  const int dblk = blockIdx.y;
  const int d0 = dblk * 64;
  const int tid = threadIdx.x;
  const size_t rowbase = (size_t)b * Nn;
  { // stage Bm/Cm
    const float* src = DBC + rowbase * 96;
#pragma unroll
    for (int k2 = 0; k2 < 16; ++k2) {
      int f = tid + k2 * 256;
      int r = f >> 5, c = f & 31;
      sBC[f] = src[r * 96 + 64 + c];
    }
  }
  // stage delta (bf16 copy), xc and res (f32 -> bf16)
#pragma unroll
  for (int k = 0; k < 8; ++k) {
    int idx = tid + k * 256;        // 2048 quads of 4 elements
    int t = idx >> 4, c4 = (idx & 15) * 4;
    *(uint2*)&sD[t * 64 + c4] = *(const uint2*)(DELTA + (rowbase + t) * 1024 + d0 + c4);
    float4 vx = *(const float4*)(XC + (rowbase + t) * 1024 + d0 + c4);
    bf16x4 px = {cvt1(vx.x), cvt1(vx.y), cvt1(vx.z), cvt1(vx.w)};
    *(bf16x4*)&sX[t * 64 + c4] = px;
    float4 vr = *(const float4*)(X2 + (rowbase + t) * 2048 + 1024 + d0 + c4);
    bf16x4 pr = {cvt1(vr.x), cvt1(vr.y), cvt1(vr.z), cvt1(vr.w)};
    *(bf16x4*)&sR[t * 64 + c4] = pr;
  }
  __syncthreads();
  const int lane = tid & 63, wave = tid >> 6;
  const int dl = lane & 15, sg = lane >> 4;
  const int dloc = wave * 16 + dl;
  const int d = d0 + dloc;
  float A_[4];
#pragma unroll
  for (int j = 0; j < 4; ++j) A_[j] = -__expf(to_f(A_log[d * Ss + sg * 4 + j]));
  const float dp = to_f(Dp[d]);
  int t = dir ? (Nn - 1) : 0;
  const int sd = dir ? -1 : 1;
  float h0 = 0.f, h1 = 0.f, h2 = 0.f, h3 = 0.f;
  for (int step = 0; step < Nn; ++step) {
    const int tc = t;
    t += sd;
    const float dv = bfraw_to_f(sD[tc * 64 + dloc]);
    const float xv = bfraw_to_f(sX[tc * 64 + dloc]);
    const float* bc = sBC + tc * 32;
    const float4 Bm = *(const float4*)(bc + sg * 4);
    const float4 Cm = *(const float4*)(bc + 16 + sg * 4);
    const float dx = dv * xv;
    h0 = __expf(dv * A_[0]) * h0 + dx * Bm.x;
    h1 = __expf(dv * A_[1]) * h1 + dx * Bm.y;
    h2 = __expf(dv * A_[2]) * h2 + dx * Bm.z;
    h3 = __expf(dv * A_[3]) * h3 + dx * Bm.w;
    float acc = h0 * Cm.x + h1 * Cm.y + h2 * Cm.z + h3 * Cm.w;
    acc += __shfl_xor(acc, 16, 64);
    acc += __shfl_xor(acc, 32, 64);
    if (sg == 0) {
      const float res = bfraw_to_f(sR[tc * 64 + dloc]);
      const float g = res / (1.f + __expf(-res));
      XC[(rowbase + tc) * 1024 + d] = (acc + xv * dp) * g;
    }
  }
}

// ---- LayerNorm (trusted R3) -----------------------------------------------
template <int MODE, typename TW>
__global__ __launch_bounds__(256) void ln_kernel(const int* __restrict__ flagp, int want,
                                                 const float* __restrict__ Z,
                                                 const float* __restrict__ Zadd,
                                                 const TW* __restrict__ g,
                                                 const TW* __restrict__ bb,
                                                 void* __restrict__ outp) {
  if (*flagp != want) return;
  const int row = blockIdx.x;
  const int tid = threadIdx.x;
  const float2* z = (const float2*)(Z + (size_t)row * Ll);
  float2 v = z[tid];
  if (MODE == 1) {
    const float2* za = (const float2*)(Zadd + (size_t)row * Ll);
    float2 a = za[tid];
    v.x += a.x;
    v.y += a.y;
  }
  float s = v.x + v.y, q = v.x * v.x + v.y * v.y;
#pragma unroll
  for (int o = 32; o > 0; o >>= 1) {
    s += __shfl_xor(s, o, 64);
    q += __shfl_xor(q, o, 64);
  }
  __shared__ float ss[4], qq[4];
  const int wv = tid >> 6, ln = tid & 63;
  if (ln == 0) { ss[wv] = s; qq[wv] = q; }
  __syncthreads();
  s = ss[0] + ss[1] + ss[2] + ss[3];
  q = qq[0] + qq[1] + qq[2] + qq[3];
  const float mean = s * (1.f / Ll);
  const float var = q * (1.f / Ll) - mean * mean;
  const float rs = rsqrtf(var + 1e-5f);
  const int c0 = tid * 2;
  const float o0 = (v.x - mean) * rs * to_f(g[c0]) + to_f(bb[c0]);
  const float o1 = (v.y - mean) * rs * to_f(g[c0 + 1]) + to_f(bb[c0 + 1]);
  if (MODE == 0) {
    float* out = (float*)outp;
    out[(size_t)row * Ll + c0] = o0;
    out[(size_t)row * Ll + c0 + 1] = o1;
  } else {
    TW* out = (TW*)outp;
    store_t(&out[(size_t)row * Ll + c0], o0);
    store_t(&out[(size_t)row * Ll + c0 + 1], o1);
  }
}

template <typename TW>
__global__ __launch_bounds__(256) void init_zbuf_kernel(const int* __restrict__ flagp, int want,
                                                        const TW* __restrict__ x,
                                                        float* __restrict__ ZB, int n) {
  if (*flagp != want) return;
  int i = blockIdx.x * 256 + threadIdx.x;
  if (i < n) ZB[i] = to_f(x[i]);
}

// ---- pipeline (dual-instantiated, flag-gated) -----------------------------
template <typename TW>
static void run_pipeline(void* const* d_in, void* d_out, const int* flagp, int want,
                         float* X2, float* XC, float* DBC, float* ZB, float* Y3,
                         hipStream_t stream) {
  const TW* x = (const TW*)d_in[0];
  const TW* in_w[2] = {(const TW*)d_in[1], (const TW*)d_in[10]};
  const TW* conv_w[2] = {(const TW*)d_in[2], (const TW*)d_in[11]};
  const TW* conv_b[2] = {(const TW*)d_in[3], (const TW*)d_in[12]};
  const TW* xproj_w[2] = {(const TW*)d_in[4], (const TW*)d_in[13]};
  const TW* dt_w[2] = {(const TW*)d_in[5], (const TW*)d_in[14]};
  const TW* dt_b[2] = {(const TW*)d_in[6], (const TW*)d_in[15]};
  const TW* A_log[2] = {(const TW*)d_in[7], (const TW*)d_in[16]};
  const TW* Dp[2] = {(const TW*)d_in[8], (const TW*)d_in[17]};
  const TW* out_w[2] = {(const TW*)d_in[9], (const TW*)d_in[18]};
  const TW* pu_w = (const TW*)d_in[19];
  const TW* pu_b = (const TW*)d_in[20];
  const TW* pl_w = (const TW*)d_in[21];
  const TW* pl_b = (const TW*)d_in[22];
  const TW* ln_g = (const TW*)d_in[23];
  const TW* ln_b = (const TW*)d_in[24];
  float* H1 = X2;            // alias: X2 dead after dir loop
  float* Z2 = XC;            // alias: XC dead after dir loop
  bf16* DELTAb = (bf16*)Y3;  // alias: Y3 (4 MB) dead during dir loop

  const dim3 blk(256);

  init_zbuf_kernel<TW><<<dim3((Mm * Ll + 255) / 256), blk, 0, stream>>>(flagp, want, x, ZB, Mm * Ll);

  for (int dir = 0; dir < 2; ++dir) {
    // X2 = x @ in_w^T  (2048x2048x512), grid 32x32 = 1024 blocks
    gemm_mfma<TW, TW, float, EPI_STORE><<<dim3(32, 32), blk, 0, stream>>>(
        flagp, want, x, Ll, in_w[dir], Ll, X2, 2048, (const TW*)nullptr, 2048, Ll);
    conv_silu_kernel<TW><<<dim3(Mm, 4), blk, 0, stream>>>(
        flagp, want, X2, conv_w[dir], conv_b[dir], XC, dir);
    // dbc = xc @ xproj_w^T  (2048x96x1024), split-K=4 -> 256 blocks, atomic
    zero_kernel<<<dim3(192), blk, 0, stream>>>((float4*)DBC, Mm * 96 / 4);
    gemm_mfma<float, TW, float, EPI_ATOMIC><<<dim3(2, 32, 4), blk, 0, stream>>>(
        flagp, want, XC, Dd, xproj_w[dir], Dd, DBC, 96, (const TW*)nullptr, 96, 256);
    // DELTA = softplus(dt @ dt_w^T + dt_b)  (2048x1024x64), grid 16x32 = 512
    gemm_mfma<float, TW, bf16, EPI_BIAS_SOFTPLUS><<<dim3(16, 32), blk, 0, stream>>>(
        flagp, want, DBC, 96, dt_w[dir], Rr, DELTAb, 1024, dt_b[dir], 1024, Rr);
    // selective scan + gating -> YG in place over XC (LDS-staged v3)
    scan_gate_kernel<TW><<<dim3(Bb, Dd / 64), blk, 0, stream>>>(
        flagp, want, DBC, XC, X2, DELTAb, A_log[dir], Dp[dir], dir);
    // ZB += YG @ out_w^T  (2048x512x1024), split-K=4 -> (8,32,4) = 1024 blocks
    gemm_mfma<float, TW, float, EPI_ATOMIC><<<dim3(8, 32, 4), blk, 0, stream>>>(
        flagp, want, XC, Dd, out_w[dir], Dd, ZB, Ll, (const TW*)nullptr, Ll, 256);
  }

  // H1raw = 0; y3 = LN(ZB)
  zero_kernel<<<dim3(Mm * Hh / 4 / 256), blk, 0, stream>>>((float4*)H1, Mm * Hh / 4);
  ln_kernel<0, TW><<<dim3(Mm), blk, 0, stream>>>(flagp, want, ZB, nullptr, ln_g, ln_b, (void*)Y3);
  // H1raw += y3 @ pu_w^T  (split-K=2 -> (32,32,2) = 2048 blocks, atomic)
  gemm_mfma<float, TW, float, EPI_ATOMIC><<<dim3(32, 32, 2), blk, 0, stream>>>(
      flagp, want, Y3, Ll, pu_w, Ll, H1, Hh, (const TW*)nullptr, Hh, 256);
  // H1 = relu(H1raw + pu_b)
  bias_relu_kernel<TW><<<dim3(Mm * Hh / 256), blk, 0, stream>>>(
      flagp, want, pu_b, H1, Mm * Hh, Hh - 1);
  // Z2 = pl_b; Z2 += H1 @ pl_w^T  (split-K=4 -> (8,32,4) = 1024 blocks, atomic)
  bias_fill_kernel<TW><<<dim3(Mm * Ll / 256), blk, 0, stream>>>(
      flagp, want, pl_b, Z2, Mm * Ll, Ll - 1);
  gemm_mfma<float, TW, float, EPI_ATOMIC><<<dim3(8, 32, 4), blk, 0, stream>>>(
      flagp, want, H1, Hh, pl_w, Hh, Z2, Ll, (const TW*)nullptr, Ll, 512);
  // out = bf16(LN(Z2 + y3))
  ln_kernel<1, TW><<<dim3(Mm), blk, 0, stream>>>(flagp, want, Z2, Y3, ln_g, ln_b, d_out);
}

extern "C" void kernel_launch(void* const* d_in, const int* in_sizes, int n_in, void* d_out,
                              int out_size, void* d_ws, size_t ws_size, hipStream_t stream) {
  char* ws = (char*)d_ws;
  int* flags = (int*)ws;
  float* X2 = (float*)(ws + 256);
  float* XC = X2 + (size_t)Mm * 2048;
  float* DBC = XC + (size_t)Mm * 1024;
  float* ZB = DBC + (size_t)Mm * 96;
  float* Y3 = ZB + (size_t)Mm * 512;
  size_t needed = 256 + sizeof(float) * ((size_t)Mm * 2048 + Mm * 1024 + Mm * 96 + Mm * 512 + Mm * 512);
  if (ws_size < needed) return;

  const dim3 blk(256);
  sniff_kernel<<<dim3(1), blk, 0, stream>>>((const unsigned short*)d_in[0], flags);

  run_pipeline<bf16>(d_in, d_out, flags, 1, X2, XC, DBC, ZB, Y3, stream);
  run_pipeline<float>(d_in, d_out, flags, 0, X2, XC, DBC, ZB, Y3, stream);

  (void)in_sizes; (void)n_in; (void)out_size;
}

// Round 13
// 475.173 us; speedup vs baseline: 1.0972x; 1.0599x over previous
//
#include <hip/hip_runtime.h>
#include <hip/hip_bf16.h>
#include <cstdint>

typedef __hip_bfloat16 bf16;

constexpr int Bb = 16, Nn = 128, Ll = 512, Dd = 1024, Ss = 16, Rr = 64, Hh = 2048;
constexpr int Mm = Bb * Nn; // 2048 rows

using bf16x8 = __attribute__((ext_vector_type(8))) __bf16;
using bf16x4 = __attribute__((ext_vector_type(4))) __bf16;
using f32x4  = __attribute__((ext_vector_type(4))) float;

__device__ __forceinline__ float to_f(float x) { return x; }
__device__ __forceinline__ float to_f(bf16 x) { return __bfloat162float(x); }
__device__ __forceinline__ void store_t(float* p, float v) { *p = v; }
__device__ __forceinline__ void store_t(bf16* p, float v) { *p = __float2bfloat16(v); }
__device__ __forceinline__ __bf16 cvt1(float x) {
  bf16 h = __float2bfloat16(x);
  return *reinterpret_cast<__bf16*>(&h);
}
__device__ __forceinline__ float bfraw_to_f(__bf16 x) {
  bf16 h = *reinterpret_cast<bf16*>(&x);
  return __bfloat162float(h);
}
__device__ __forceinline__ bf16x8 load8(const bf16* p) { return *(const bf16x8*)p; }
__device__ __forceinline__ bf16x8 load8(const float* p) {
  float4 a = *(const float4*)p;
  float4 b = *(const float4*)(p + 4);
  bf16x8 r;
  r[0] = cvt1(a.x); r[1] = cvt1(a.y); r[2] = cvt1(a.z); r[3] = cvt1(a.w);
  r[4] = cvt1(b.x); r[5] = cvt1(b.y); r[6] = cvt1(b.z); r[7] = cvt1(b.w);
  return r;
}

enum { EPI_STORE = 0, EPI_BIAS_RELU = 1, EPI_ADD = 3, EPI_BIAS = 4, EPI_BIAS_SOFTPLUS = 5,
       EPI_ATOMIC = 6 };

// ---- dtype sniffer --------------------------------------------------------
__global__ void sniff_kernel(const unsigned short* __restrict__ xs, int* __restrict__ flags) {
  const int tid = threadIdx.x;
  int cnt = 0;
  for (int j = 0; j < 64; ++j) {
    int i = tid + j * 256;
    unsigned short u = xs[(size_t)i * 64];
    bf16 h = *reinterpret_cast<bf16*>(&u);
    float v = __bfloat162float(h);
    float a = fabsf(v);
    if (v == 0.f || (a > 0.0009765625f && a < 16.f)) ++cnt;
  }
  __shared__ int sc[256];
  sc[tid] = cnt;
  __syncthreads();
  for (int o = 128; o > 0; o >>= 1) {
    if (tid < o) sc[tid] += sc[tid + o];
    __syncthreads();
  }
  if (tid == 0) flags[0] = (sc[0] > 8192) ? 1 : 0; // 1 = bf16, 0 = f32
}

// ---- MFMA GEMM (green core since R8): 64x64 tile, BK=64, split-K grid.z ----
constexpr int LDT2 = 72; // row stride el: 144 B, 16B-aligned
template <typename TA, typename TW, typename TC, int EPI>
__global__ __launch_bounds__(256) void gemm_mfma(const int* __restrict__ flagp, int want,
                                                 const TA* __restrict__ A, int lda,
                                                 const TW* __restrict__ Bw, int ldb,
                                                 TC* __restrict__ C, int ldc,
                                                 const TW* __restrict__ bias,
                                                 int N, int Kchunk) {
  if (*flagp != want) return;
  __shared__ __align__(16) __bf16 As[64 * LDT2];
  __shared__ __align__(16) __bf16 Bs[64 * LDT2];
  const int tid = threadIdx.x;
  const int wave = tid >> 6, lane = tid & 63;
  const int quad = lane >> 4, l16 = lane & 15;
  const int wm = wave & 1, wn = wave >> 1;
  int bx = blockIdx.x, by = blockIdx.y;
  const int gx = gridDim.x, gy = gridDim.y;
  if ((gx & 7) == 0) { // XCD swizzle (bijection)
    int id = bx + gx * by;
    int xcd = id & 7, sl = id >> 3;
    by = sl % gy;
    bx = (sl / gy) * 8 + xcd;
  }
  const int m0 = by * 64, n0 = bx * 64;
  const int kb = blockIdx.z * Kchunk;
  const int srow = tid >> 3;      // 0..31
  const int scol = (tid & 7) * 8; // 0..56
  f32x4 acc[2][2] = {};
  for (int k0 = kb; k0 < kb + Kchunk; k0 += 64) {
#pragma unroll
    for (int h = 0; h < 2; ++h) {
      int r = srow + h * 32;
      *(bf16x8*)(&As[r * LDT2 + scol]) = load8(A + (size_t)(m0 + r) * lda + k0 + scol);
      int rb = n0 + r;
      rb = rb < N ? rb : N - 1; // clamp (ragged N); garbage cols masked in epilogue
      *(bf16x8*)(&Bs[r * LDT2 + scol]) = load8(Bw + (size_t)rb * ldb + k0 + scol);
    }
    __syncthreads();
#pragma unroll
    for (int kk = 0; kk < 2; ++kk) {
      bf16x8 af[2], bfr[2];
#pragma unroll
      for (int i = 0; i < 2; ++i)
        af[i] = *(const bf16x8*)(&As[(wm * 32 + i * 16 + l16) * LDT2 + kk * 32 + quad * 8]);
#pragma unroll
      for (int j = 0; j < 2; ++j)
        bfr[j] = *(const bf16x8*)(&Bs[(wn * 32 + j * 16 + l16) * LDT2 + kk * 32 + quad * 8]);
#pragma unroll
      for (int i = 0; i < 2; ++i)
#pragma unroll
        for (int j = 0; j < 2; ++j)
          acc[i][j] = __builtin_amdgcn_mfma_f32_16x16x32_bf16(af[i], bfr[j], acc[i][j], 0, 0, 0);
    }
    __syncthreads();
  }
#pragma unroll
  for (int i = 0; i < 2; ++i) {
#pragma unroll
    for (int j = 0; j < 2; ++j) {
      const int col = n0 + wn * 32 + j * 16 + l16;
      if (col >= N) continue;
      float bv = 0.f;
      if (EPI == EPI_BIAS_RELU || EPI == EPI_BIAS || EPI == EPI_BIAS_SOFTPLUS) bv = to_f(bias[col]);
#pragma unroll
      for (int r = 0; r < 4; ++r) {
        const int row = m0 + wm * 32 + i * 16 + quad * 4 + r;
        size_t idx = (size_t)row * ldc + col;
        float v = acc[i][j][r];
        if (EPI == EPI_STORE) store_t(&C[idx], v);
        else if (EPI == EPI_BIAS_RELU) { v += bv; store_t(&C[idx], v > 0.f ? v : 0.f); }
        else if (EPI == EPI_ADD) ((float*)C)[idx] += v;        // TC=float only
        else if (EPI == EPI_BIAS) store_t(&C[idx], v + bv);
        else if (EPI == EPI_BIAS_SOFTPLUS) {
          v += bv;
          store_t(&C[idx], (v > 20.f) ? v : log1pf(__expf(v)));
        } else if (EPI == EPI_ATOMIC) {
          atomicAdd((float*)&C[idx], v);                        // TC=float only
        }
      }
    }
  }
}

// ---- helpers --------------------------------------------------------------
__global__ __launch_bounds__(256) void zero_kernel(float4* __restrict__ p, int n4) {
  int i = blockIdx.x * 256 + threadIdx.x;
  if (i < n4) p[i] = float4{0.f, 0.f, 0.f, 0.f};
}

template <typename TW>
__global__ __launch_bounds__(256) void bias_fill_kernel(const int* __restrict__ flagp, int want,
                                                        const TW* __restrict__ bias,
                                                        float* __restrict__ Z, int n, int cmask) {
  if (*flagp != want) return;
  int i = blockIdx.x * 256 + threadIdx.x;
  if (i < n) Z[i] = to_f(bias[i & cmask]);
}

template <typename TW>
__global__ __launch_bounds__(256) void bias_relu_kernel(const int* __restrict__ flagp, int want,
                                                        const TW* __restrict__ bias,
                                                        float* __restrict__ H, int n, int cmask) {
  if (*flagp != want) return;
  int i = blockIdx.x * 256 + threadIdx.x;
  if (i < n) {
    float v = H[i] + to_f(bias[i & cmask]);
    H[i] = v > 0.f ? v : 0.f;
  }
}

// ---- depthwise conv + SiLU (trusted R3) -----------------------------------
template <typename TW>
__global__ __launch_bounds__(256) void conv_silu_kernel(const int* __restrict__ flagp, int want,
                                                        const float* __restrict__ X2,
                                                        const TW* __restrict__ cw,
                                                        const TW* __restrict__ cb,
                                                        float* __restrict__ XC, int dir) {
  if (*flagp != want) return;
  const int d = blockIdx.y * 256 + threadIdx.x;
  const int m = blockIdx.x;
  const int t = m & (Nn - 1);
  float w0 = to_f(cw[d * 4 + 0]), w1 = to_f(cw[d * 4 + 1]);
  float w2 = to_f(cw[d * 4 + 2]), w3 = to_f(cw[d * 4 + 3]);
  float a = to_f(cb[d]);
  if (dir == 0) {
    if (t >= 3) a += w0 * X2[(size_t)(m - 3) * 2048 + d];
    if (t >= 2) a += w1 * X2[(size_t)(m - 2) * 2048 + d];
    if (t >= 1) a += w2 * X2[(size_t)(m - 1) * 2048 + d];
    a += w3 * X2[(size_t)m * 2048 + d];
  } else {
    if (t + 3 < Nn) a += w0 * X2[(size_t)(m + 3) * 2048 + d];
    if (t + 2 < Nn) a += w1 * X2[(size_t)(m + 2) * 2048 + d];
    if (t + 1 < Nn) a += w2 * X2[(size_t)(m + 1) * 2048 + d];
    a += w3 * X2[(size_t)m * 2048 + d];
  }
  XC[(size_t)m * 1024 + d] = a / (1.f + __expf(-a));
}

// ---- selective scan v4: chunked 2-pass scan, 4 t-chunks per block ----------
// Block = (b, 16 d's), 256 thr = 4 waves; wave q owns process-chunk q (32 steps).
// Decomposition: h_p = exp(A*Sdv_p) (.) h_init + h_local_p, with Sdv_p the
// inclusive cumsum of delta in process order within the chunk. Pass 1 scans
// each chunk from h=0 (partial y -> XC), recording Sdv per t and chunk-end
// states. Wave 0 serially combines 4 chunk transitions (per d). Pass 2 adds
// the elementwise correction y_p += C_p . (exp(A*Sdv_p) (.) h_init[q]) and
// applies D-skip + SiLU gating. Grid (16,64) = 1024 blocks = 4 blocks/CU.
template <typename TW>
__global__ __launch_bounds__(256) void scan_gate_kernel(
    const int* __restrict__ flagp, int want,
    const float* __restrict__ DBC, float* __restrict__ XC, const float* __restrict__ X2,
    const bf16* __restrict__ DELTA,
    const TW* __restrict__ A_log, const TW* __restrict__ Dp, int dir) {
  if (*flagp != want) return;
  __shared__ __align__(16) __bf16 sBC[Nn * 32];  // Bm|Cm per t        8 KB
  __shared__ __align__(16) __bf16 sD[Nn * 16];   // delta              4 KB
  __shared__ __align__(16) __bf16 sX[Nn * 16];   // xc                 4 KB
  __shared__ __align__(16) __bf16 sR[Nn * 16];   // res                4 KB
  __shared__ float sSdv[Nn * 16];                // incl. cumsum(dv)   8 KB
  __shared__ float sHend[4 * 16 * 16];           // [q][s][dl]         4 KB
  __shared__ float sSdvEnd[4 * 16];              // [q][dl]          256 B
  const int b = blockIdx.x;
  const int d0 = blockIdx.y * 16;
  const int tid = threadIdx.x;
  const size_t rowbase = (size_t)b * Nn;
  // ---- stage ----
#pragma unroll
  for (int k = 0; k < 16; ++k) {
    int idx = tid + k * 256;
    int t = idx >> 5, c = idx & 31;
    sBC[idx] = cvt1(DBC[(rowbase + t) * 96 + 64 + c]);
  }
  {
    int t = tid >> 1, h = tid & 1;
    *(uint4*)&sD[t * 16 + h * 8] = *(const uint4*)(DELTA + (rowbase + t) * 1024 + d0 + h * 8);
  }
#pragma unroll
  for (int k = 0; k < 2; ++k) {
    int j = tid + k * 256;
    int t = j >> 2, qq = j & 3;
    float4 vx = *(const float4*)(XC + (rowbase + t) * 1024 + d0 + qq * 4);
    bf16x4 px = {cvt1(vx.x), cvt1(vx.y), cvt1(vx.z), cvt1(vx.w)};
    *(bf16x4*)&sX[t * 16 + qq * 4] = px;
    float4 vr = *(const float4*)(X2 + (rowbase + t) * 2048 + 1024 + d0 + qq * 4);
    bf16x4 pr = {cvt1(vr.x), cvt1(vr.y), cvt1(vr.z), cvt1(vr.w)};
    *(bf16x4*)&sR[t * 16 + qq * 4] = pr;
  }
  __syncthreads();
  const int q = tid >> 6;  // wave = process-chunk
  const int lane = tid & 63;
  const int dl = lane & 15, sg = lane >> 4;
  const int d = d0 + dl;
  float A_[4];
#pragma unroll
  for (int j = 0; j < 4; ++j) A_[j] = -__expf(to_f(A_log[d * Ss + sg * 4 + j]));
  // ---- pass 1: chunk-local scan from h=0 ----
  float h0 = 0.f, h1 = 0.f, h2 = 0.f, h3 = 0.f, Sdv = 0.f;
  for (int j = 0; j < 32; ++j) {
    const int p = q * 32 + j;
    const int t = dir ? (Nn - 1 - p) : p;
    const float dv = bfraw_to_f(sD[t * 16 + dl]);
    const float xv = bfraw_to_f(sX[t * 16 + dl]);
    Sdv += dv;
    bf16x4 Bmv = *(const bf16x4*)&sBC[t * 32 + sg * 4];
    bf16x4 Cmv = *(const bf16x4*)&sBC[t * 32 + 16 + sg * 4];
    const float dx = dv * xv;
    h0 = __expf(dv * A_[0]) * h0 + dx * bfraw_to_f(Bmv[0]);
    h1 = __expf(dv * A_[1]) * h1 + dx * bfraw_to_f(Bmv[1]);
    h2 = __expf(dv * A_[2]) * h2 + dx * bfraw_to_f(Bmv[2]);
    h3 = __expf(dv * A_[3]) * h3 + dx * bfraw_to_f(Bmv[3]);
    float acc = h0 * bfraw_to_f(Cmv[0]) + h1 * bfraw_to_f(Cmv[1]) +
                h2 * bfraw_to_f(Cmv[2]) + h3 * bfraw_to_f(Cmv[3]);
    acc += __shfl_xor(acc, 16, 64);
    acc += __shfl_xor(acc, 32, 64);
    if (sg == 0) {
      sSdv[t * 16 + dl] = Sdv;
      XC[(rowbase + t) * 1024 + d] = acc; // partial y
    }
  }
  sHend[q * 256 + (sg * 4 + 0) * 16 + dl] = h0;
  sHend[q * 256 + (sg * 4 + 1) * 16 + dl] = h1;
  sHend[q * 256 + (sg * 4 + 2) * 16 + dl] = h2;
  sHend[q * 256 + (sg * 4 + 3) * 16 + dl] = h3;
  if (sg == 0) sSdvEnd[q * 16 + dl] = Sdv;
  __syncthreads();
  // ---- combine: wave 0 propagates chunk transitions (process order) ----
  if (q == 0) {
    float r0 = 0.f, r1 = 0.f, r2 = 0.f, r3 = 0.f;
    for (int qq = 0; qq < 4; ++qq) {
      const float se = sSdvEnd[qq * 16 + dl];
      const float e0 = __expf(A_[0] * se), e1 = __expf(A_[1] * se);
      const float e2 = __expf(A_[2] * se), e3 = __expf(A_[3] * se);
      const int base = qq * 256 + sg * 4 * 16 + dl;
      float t0 = sHend[base + 0 * 16], t1 = sHend[base + 1 * 16];
      float t2 = sHend[base + 2 * 16], t3 = sHend[base + 3 * 16];
      sHend[base + 0 * 16] = r0; sHend[base + 1 * 16] = r1; // now h_init[qq]
      sHend[base + 2 * 16] = r2; sHend[base + 3 * 16] = r3;
      r0 = e0 * r0 + t0; r1 = e1 * r1 + t1;
      r2 = e2 * r2 + t2; r3 = e3 * r3 + t3;
    }
  }
  __syncthreads();
  // ---- pass 2: elementwise correction + gating (no recurrence) ----
  {
    const int dl2 = lane & 15, trow = lane >> 4;
    const int d2 = d0 + dl2;
    float A2[16];
#pragma unroll
    for (int s = 0; s < 16; ++s) A2[s] = -__expf(to_f(A_log[d2 * Ss + s]));
    const float dp2 = to_f(Dp[d2]);
    float hin[16];
#pragma unroll
    for (int s = 0; s < 16; ++s) hin[s] = sHend[q * 256 + s * 16 + dl2];
    for (int rep = 0; rep < 8; ++rep) {
      const int p = q * 32 + trow + rep * 4;
      const int t = dir ? (Nn - 1 - p) : p;
      const float Sv = sSdv[t * 16 + dl2];
      float corr = 0.f;
#pragma unroll
      for (int s = 0; s < 16; ++s)
        corr += bfraw_to_f(sBC[t * 32 + 16 + s]) * __expf(A2[s] * Sv) * hin[s];
      const size_t gidx = (rowbase + t) * 1024 + d2;
      const float y = XC[gidx] + corr;
      const float xv = bfraw_to_f(sX[t * 16 + dl2]);
      const float res = bfraw_to_f(sR[t * 16 + dl2]);
      const float g = res / (1.f + __expf(-res));
      XC[gidx] = (y + xv * dp2) * g;
    }
  }
}

// ---- LayerNorm (trusted R3) -----------------------------------------------
template <int MODE, typename TW>
__global__ __launch_bounds__(256) void ln_kernel(const int* __restrict__ flagp, int want,
                                                 const float* __restrict__ Z,
                                                 const float* __restrict__ Zadd,
                                                 const TW* __restrict__ g,
                                                 const TW* __restrict__ bb,
                                                 void* __restrict__ outp) {
  if (*flagp != want) return;
  const int row = blockIdx.x;
  const int tid = threadIdx.x;
  const float2* z = (const float2*)(Z + (size_t)row * Ll);
  float2 v = z[tid];
  if (MODE == 1) {
    const float2* za = (const float2*)(Zadd + (size_t)row * Ll);
    float2 a = za[tid];
    v.x += a.x;
    v.y += a.y;
  }
  float s = v.x + v.y, q = v.x * v.x + v.y * v.y;
#pragma unroll
  for (int o = 32; o > 0; o >>= 1) {
    s += __shfl_xor(s, o, 64);
    q += __shfl_xor(q, o, 64);
  }
  __shared__ float ss[4], qq[4];
  const int wv = tid >> 6, ln = tid & 63;
  if (ln == 0) { ss[wv] = s; qq[wv] = q; }
  __syncthreads();
  s = ss[0] + ss[1] + ss[2] + ss[3];
  q = qq[0] + qq[1] + qq[2] + qq[3];
  const float mean = s * (1.f / Ll);
  const float var = q * (1.f / Ll) - mean * mean;
  const float rs = rsqrtf(var + 1e-5f);
  const int c0 = tid * 2;
  const float o0 = (v.x - mean) * rs * to_f(g[c0]) + to_f(bb[c0]);
  const float o1 = (v.y - mean) * rs * to_f(g[c0 + 1]) + to_f(bb[c0 + 1]);
  if (MODE == 0) {
    float* out = (float*)outp;
    out[(size_t)row * Ll + c0] = o0;
    out[(size_t)row * Ll + c0 + 1] = o1;
  } else {
    TW* out = (TW*)outp;
    store_t(&out[(size_t)row * Ll + c0], o0);
    store_t(&out[(size_t)row * Ll + c0 + 1], o1);
  }
}

template <typename TW>
__global__ __launch_bounds__(256) void init_zbuf_kernel(const int* __restrict__ flagp, int want,
                                                        const TW* __restrict__ x,
                                                        float* __restrict__ ZB, int n) {
  if (*flagp != want) return;
  int i = blockIdx.x * 256 + threadIdx.x;
  if (i < n) ZB[i] = to_f(x[i]);
}

// ---- pipeline (dual-instantiated, flag-gated) -----------------------------
template <typename TW>
static void run_pipeline(void* const* d_in, void* d_out, const int* flagp, int want,
                         float* X2, float* XC, float* DBC, float* ZB, float* Y3,
                         hipStream_t stream) {
  const TW* x = (const TW*)d_in[0];
  const TW* in_w[2] = {(const TW*)d_in[1], (const TW*)d_in[10]};
  const TW* conv_w[2] = {(const TW*)d_in[2], (const TW*)d_in[11]};
  const TW* conv_b[2] = {(const TW*)d_in[3], (const TW*)d_in[12]};
  const TW* xproj_w[2] = {(const TW*)d_in[4], (const TW*)d_in[13]};
  const TW* dt_w[2] = {(const TW*)d_in[5], (const TW*)d_in[14]};
  const TW* dt_b[2] = {(const TW*)d_in[6], (const TW*)d_in[15]};
  const TW* A_log[2] = {(const TW*)d_in[7], (const TW*)d_in[16]};
  const TW* Dp[2] = {(const TW*)d_in[8], (const TW*)d_in[17]};
  const TW* out_w[2] = {(const TW*)d_in[9], (const TW*)d_in[18]};
  const TW* pu_w = (const TW*)d_in[19];
  const TW* pu_b = (const TW*)d_in[20];
  const TW* pl_w = (const TW*)d_in[21];
  const TW* pl_b = (const TW*)d_in[22];
  const TW* ln_g = (const TW*)d_in[23];
  const TW* ln_b = (const TW*)d_in[24];
  float* H1 = X2;            // alias: X2 dead after dir loop
  float* Z2 = XC;            // alias: XC dead after dir loop
  bf16* DELTAb = (bf16*)Y3;  // alias: Y3 (4 MB) dead during dir loop

  const dim3 blk(256);

  init_zbuf_kernel<TW><<<dim3((Mm * Ll + 255) / 256), blk, 0, stream>>>(flagp, want, x, ZB, Mm * Ll);

  for (int dir = 0; dir < 2; ++dir) {
    // X2 = x @ in_w^T  (2048x2048x512), grid 32x32 = 1024 blocks
    gemm_mfma<TW, TW, float, EPI_STORE><<<dim3(32, 32), blk, 0, stream>>>(
        flagp, want, x, Ll, in_w[dir], Ll, X2, 2048, (const TW*)nullptr, 2048, Ll);
    conv_silu_kernel<TW><<<dim3(Mm, 4), blk, 0, stream>>>(
        flagp, want, X2, conv_w[dir], conv_b[dir], XC, dir);
    // dbc = xc @ xproj_w^T  (2048x96x1024), split-K=4 -> 256 blocks, atomic
    zero_kernel<<<dim3(192), blk, 0, stream>>>((float4*)DBC, Mm * 96 / 4);
    gemm_mfma<float, TW, float, EPI_ATOMIC><<<dim3(2, 32, 4), blk, 0, stream>>>(
        flagp, want, XC, Dd, xproj_w[dir], Dd, DBC, 96, (const TW*)nullptr, 96, 256);
    // DELTA = softplus(dt @ dt_w^T + dt_b)  (2048x1024x64), grid 16x32 = 512
    gemm_mfma<float, TW, bf16, EPI_BIAS_SOFTPLUS><<<dim3(16, 32), blk, 0, stream>>>(
        flagp, want, DBC, 96, dt_w[dir], Rr, DELTAb, 1024, dt_b[dir], 1024, Rr);
    // selective scan + gating -> YG in place over XC (chunked v4)
    scan_gate_kernel<TW><<<dim3(Bb, Dd / 16), blk, 0, stream>>>(
        flagp, want, DBC, XC, X2, DELTAb, A_log[dir], Dp[dir], dir);
    // ZB += YG @ out_w^T  (2048x512x1024), split-K=4 -> (8,32,4) = 1024 blocks
    gemm_mfma<float, TW, float, EPI_ATOMIC><<<dim3(8, 32, 4), blk, 0, stream>>>(
        flagp, want, XC, Dd, out_w[dir], Dd, ZB, Ll, (const TW*)nullptr, Ll, 256);
  }

  // H1raw = 0; y3 = LN(ZB)
  zero_kernel<<<dim3(Mm * Hh / 4 / 256), blk, 0, stream>>>((float4*)H1, Mm * Hh / 4);
  ln_kernel<0, TW><<<dim3(Mm), blk, 0, stream>>>(flagp, want, ZB, nullptr, ln_g, ln_b, (void*)Y3);
  // H1raw += y3 @ pu_w^T  (split-K=2 -> (32,32,2) = 2048 blocks, atomic)
  gemm_mfma<float, TW, float, EPI_ATOMIC><<<dim3(32, 32, 2), blk, 0, stream>>>(
      flagp, want, Y3, Ll, pu_w, Ll, H1, Hh, (const TW*)nullptr, Hh, 256);
  // H1 = relu(H1raw + pu_b)
  bias_relu_kernel<TW><<<dim3(Mm * Hh / 256), blk, 0, stream>>>(
      flagp, want, pu_b, H1, Mm * Hh, Hh - 1);
  // Z2 = pl_b; Z2 += H1 @ pl_w^T  (split-K=4 -> (8,32,4) = 1024 blocks, atomic)
  bias_fill_kernel<TW><<<dim3(Mm * Ll / 256), blk, 0, stream>>>(
      flagp, want, pl_b, Z2, Mm * Ll, Ll - 1);
  gemm_mfma<float, TW, float, EPI_ATOMIC><<<dim3(8, 32, 4), blk, 0, stream>>>(
      flagp, want, H1, Hh, pl_w, Hh, Z2, Ll, (const TW*)nullptr, Ll, 512);
  // out = bf16(LN(Z2 + y3))
  ln_kernel<1, TW><<<dim3(Mm), blk, 0, stream>>>(flagp, want, Z2, Y3, ln_g, ln_b, d_out);
}

extern "C" void kernel_launch(void* const* d_in, const int* in_sizes, int n_in, void* d_out,
                              int out_size, void* d_ws, size_t ws_size, hipStream_t stream) {
  char* ws = (char*)d_ws;
  int* flags = (int*)ws;
  float* X2 = (float*)(ws + 256);
  float* XC = X2 + (size_t)Mm * 2048;
  float* DBC = XC + (size_t)Mm * 1024;
  float* ZB = DBC + (size_t)Mm * 96;
  float* Y3 = ZB + (size_t)Mm * 512;
  size_t needed = 256 + sizeof(float) * ((size_t)Mm * 2048 + Mm * 1024 + Mm * 96 + Mm * 512 + Mm * 512);
  if (ws_size < needed) return;

  const dim3 blk(256);
  sniff_kernel<<<dim3(1), blk, 0, stream>>>((const unsigned short*)d_in[0], flags);

  run_pipeline<bf16>(d_in, d_out, flags, 1, X2, XC, DBC, ZB, Y3, stream);
  run_pipeline<float>(d_in, d_out, flags, 0, X2, XC, DBC, ZB, Y3, stream);

  (void)in_sizes; (void)n_in; (void)out_size;
}